// Round 1
// baseline (60.990 us; speedup 1.0000x reference)
//
#include <hip/hip_runtime.h>

#define MAX_LEN 16384
#define RES_LEN 16372   // (16384 - 4) - 9 + 1
#define P1_LEN  16364   // RES_LEN - 9 + 1   (stride-1 pool length)
#define P2_LEN  1819    // (RES_LEN - 9)/9 + 1 (stride-9 pool length)

__global__ __launch_bounds__(512, 2)
void derive_kernel(const float* __restrict__ x, float* __restrict__ out) {
    const int b = blockIdx.x >> 2;
    const int c = blockIdx.x & 3;
    const float* __restrict__ xr = x + (size_t)b * MAX_LEN;

    __shared__ float resS[RES_LEN + 4];
    __shared__ float a2S[P2_LEN + 1];
    __shared__ float m2S[P2_LEN + 1];

    const float inv9 = 1.0f / 9.0f;
    const int tid = threadIdx.x;

    // Phase 1: res (telescoped 9-wide avg of the shifted differences).
    // res[j] = (1/9) * sum_{t=j+4}^{j+12} r[t],  r depends on channel c.
    if (c == 0) {
        for (int j = tid; j < RES_LEN; j += 512) {
            float W = xr[j + 12] - xr[j + 3];
            resS[j] = W * inv9;
        }
    } else if (c == 1) {
        for (int j = tid; j < RES_LEN; j += 512) {
            float W = (xr[j + 12] + xr[j + 11]) - (xr[j + 3] + xr[j + 2]);
            resS[j] = W * inv9;
        }
    } else if (c == 2) {
        for (int j = tid; j < RES_LEN; j += 512) {
            float W = (xr[j + 9] + xr[j + 10] + xr[j + 11] + xr[j + 12])
                    - (xr[j] + xr[j + 1] + xr[j + 2] + xr[j + 3]);
            resS[j] = W * inv9;
        }
    } else {
        for (int j = tid; j < RES_LEN; j += 512) {
            float W = (xr[j + 12] - xr[j + 11]) - (xr[j + 3] - xr[j + 2]);
            resS[j] = W * inv9;
        }
    }
    __syncthreads();

    // Phase 2: stride-9 avg/max pools (small arrays). Lane stride 9 floats
    // is coprime with 32 banks -> <=2-way aliasing (free).
    for (int p = tid; p < P2_LEN; p += 512) {
        const int j0 = 9 * p;
        float v = resS[j0];
        float s = v, m = v;
        #pragma unroll
        for (int k = 1; k < 9; ++k) {
            float w = resS[j0 + k];
            s += w;
            m = fmaxf(m, w);
        }
        a2S[p] = s * inv9;
        m2S[p] = m;
    }
    __syncthreads();

    // Phase 3: the 4 branch outputs. One 9-wide window read serves both the
    // stride-1 avg and stride-1 max branches.
    float* __restrict__ outBase = out + ((size_t)b * 16 + c) * RES_LEN;
    for (int i = tid; i < RES_LEN; i += 512) {
        const unsigned p1 = ((unsigned)i * 16364u) / 16372u;
        const unsigned p2 = ((unsigned)i * 1819u) / 16372u;

        float v = resS[p1];
        float s = v, m = v;
        #pragma unroll
        for (int k = 1; k < 9; ++k) {
            float w = resS[p1 + k];
            s += w;
            m = fmaxf(m, w);
        }
        const float r = resS[i];

        outBase[i]                    = s * inv9 + r;  // upsampled avgpool(9,1) + res
        outBase[4 * RES_LEN + i]      = a2S[p2] + r;   // upsampled avgpool(9,9) + res
        outBase[8 * RES_LEN + i]      = m + r;         // upsampled maxpool(9,1) + res
        outBase[12 * RES_LEN + i]     = m2S[p2] + r;   // upsampled maxpool(9,9) + res
    }
}

extern "C" void kernel_launch(void* const* d_in, const int* in_sizes, int n_in,
                              void* d_out, int out_size, void* d_ws, size_t ws_size,
                              hipStream_t stream) {
    const float* x = (const float*)d_in[0];
    float* out = (float*)d_out;
    // 256 batches x 4 res-channels; one block per (b, c).
    derive_kernel<<<dim3(256 * 4), dim3(512), 0, stream>>>(x, out);
}